// Round 1
// baseline (460.371 us; speedup 1.0000x reference)
//
#include <hip/hip_runtime.h>
#include <hip/hip_bf16.h>

// Problem constants (fixed shapes from setup_inputs):
// N=500000, F=128, B=1024, K=256, E=4000000
constexpr int F = 128;
constexpr int K = 256;

// ---------------- importance chain ----------------

__global__ void zero_kernel(float* p, int n) {
    int i = blockIdx.x * blockDim.x + threadIdx.x;
    if (i < n) p[i] = 0.0f;
}

__global__ void deg_kernel(const int* __restrict__ row, int E, int* cnt) {
    int e = blockIdx.x * blockDim.x + threadIdx.x;
    if (e < E) atomicAdd(&cnt[row[e]], 1);
}

// in-place: read int count, write float deg_inv (same buffer)
__global__ void deginv_kernel(int* buf, int N) {
    int i = blockIdx.x * blockDim.x + threadIdx.x;
    if (i < N) {
        int c = buf[i];
        float dinv = 1.0f / (float)(c + 1);   // +1 self loop; deg always > 0
        ((float*)buf)[i] = dinv;
    }
}

__global__ void nbrsum_kernel(const int* __restrict__ row, const int* __restrict__ col,
                              int E, const float* __restrict__ deg_inv, float* nbr_sum) {
    int e = blockIdx.x * blockDim.x + threadIdx.x;
    if (e < E) atomicAdd(&nbr_sum[row[e]], deg_inv[col[e]]);
}

// in-place: nbr_sum buffer becomes n_imp
__global__ void nimp_kernel(const float* __restrict__ deg_inv, float* buf, int N) {
    int i = blockIdx.x * blockDim.x + threadIdx.x;
    if (i < N) {
        float dinv = deg_inv[i];
        float s = dinv * (buf[i] + dinv);
        buf[i] = sqrtf(fmaxf(s, 0.0f));
    }
}

// ---------------- fused scoring + aggregation ----------------
// One block per root b. Stage x_u[b] (256x128 f32 = 128KB) in LDS once.

__global__ __launch_bounds__(512) void sampler_main(
    const float* __restrict__ x,
    const float* __restrict__ w_ego_root,
    const float* __restrict__ w_ego_u,
    const float* __restrict__ w_layer_v,
    const float* __restrict__ w_layer_u,
    const int* __restrict__ roots,
    const int* __restrict__ neighbors,
    const float* __restrict__ n_imp,
    float* __restrict__ out)
{
    __shared__ __align__(16) float tile[K][F];   // 128 KB
    __shared__ float g_s[F];      // x_root*w_ego_root*w_ego_u  (ego dot weights)
    __shared__ float weu_s[F];    // w_ego_u
    __shared__ float wlu_s[F];    // w_layer_u
    __shared__ float ego_s[K];
    __shared__ float pre_s[K];
    __shared__ float praw_s[K];
    __shared__ float wgt_s[K];
    __shared__ float part_s[4][F];
    __shared__ float scal_s[4];   // [0]=na (clamped), [1]=h_v, [2]=layer norm
    __shared__ int   nbr_s[K];

    const int b = blockIdx.x;
    const int t = threadIdx.x;
    const int root = roots[b];
    const int* nbr = neighbors + (size_t)b * K;

    if (t < K) nbr_s[t] = nbr[t];
    if (t < F) {
        float xr  = x[(size_t)root * F + t];
        float hr  = xr * w_ego_root[t];
        float weu = w_ego_u[t];
        g_s[t]   = hr * weu;
        weu_s[t] = weu;
        wlu_s[t] = w_layer_u[t];
        pre_s[t] = hr * hr;                 // temp: na^2 partials
        ego_s[t] = xr * w_layer_v[t];       // temp: h_v partials
    }
    __syncthreads();

    // wave 0: reduce na^2 and h_v over 128 temps
    if (t < 64) {
        float a = pre_s[t] + pre_s[t + 64];
        float h = ego_s[t] + ego_s[t + 64];
        for (int m = 1; m < 64; m <<= 1) {
            a += __shfl_xor(a, m);
            h += __shfl_xor(h, m);
        }
        if (t == 0) {
            scal_s[0] = fmaxf(sqrtf(a), 1e-6f);
            scal_s[1] = h;
        }
    }

    // all threads: stage x_u tile into LDS (16B per lane, coalesced per row)
    for (int idx = t; idx < K * (F / 4); idx += 512) {
        int k  = idx >> 5;          // F/4 == 32 float4 per row
        int f4 = idx & 31;
        float4 v = ((const float4*)(x + (size_t)nbr_s[k] * F))[f4];
        ((float4*)tile[k])[f4] = v;
    }
    __syncthreads();

    // scoring: wave w handles k = w, w+8, ...; lane owns 2 features
    {
        const int wave = t >> 6;
        const int lane = t & 63;
        const float na = scal_s[0];
        const float hv = scal_s[1];
        const int f0 = lane * 2;
        const float g0 = g_s[f0],  g1 = g_s[f0 + 1];
        const float e0w = weu_s[f0], e1w = weu_s[f0 + 1];
        const float l0 = wlu_s[f0], l1 = wlu_s[f0 + 1];
        for (int k = wave; k < K; k += 8) {
            float2 v = ((const float2*)tile[k])[lane];
            float d   = g0 * v.x + g1 * v.y;
            float u0  = v.x * e0w, u1 = v.y * e1w;
            float nb2 = u0 * u0 + u1 * u1;
            float hu  = l0 * v.x + l1 * v.y;
            for (int m = 1; m < 64; m <<= 1) {
                d   += __shfl_xor(d, m);
                nb2 += __shfl_xor(nb2, m);
                hu  += __shfl_xor(hu, m);
            }
            if (lane == 0) {
                float nb = fmaxf(sqrtf(nb2), 1e-6f);
                ego_s[k] = d / (na * nb);
                pre_s[k] = fmaxf(hv + hu, 0.0f);
            }
        }
    }
    __syncthreads();

    // layer norm over k
    if (t < 64) {
        float s = 0.0f;
        for (int k = t; k < K; k += 64) s += pre_s[k] * pre_s[k];
        for (int m = 1; m < 64; m <<= 1) s += __shfl_xor(s, m);
        if (t == 0) scal_s[2] = fmaxf(sqrtf(s), 1e-12f);
    }
    __syncthreads();

    if (t < K) {
        float layer = pre_s[t] / scal_s[2];
        praw_s[t] = (0.5f * ego_s[t] + 0.5f * layer) * n_imp[nbr_s[t]];
    }
    __syncthreads();

    if (t < K) {
        float pn = praw_s[0] + 1e-7f;
        float pu = praw_s[t] / pn + 1.0f;
        float pc = fminf(fmaxf(pu, 0.01f), 1.0f);
        wgt_s[t] = (pu > 0.0f) ? pc : 0.0f;
    }
    __syncthreads();

    // weighted aggregation out[b,f] = sum_k w[k] * tile[k][f]
    {
        int f   = t & (F - 1);
        int grp = t >> 7;           // 4 groups of 64 k each
        float acc = 0.0f;
        int k0 = grp * 64;
        for (int k = k0; k < k0 + 64; ++k)
            acc += wgt_s[k] * tile[k][f];
        part_s[grp][f] = acc;
    }
    __syncthreads();

    if (t < F) {
        out[(size_t)b * F + t] =
            part_s[0][t] + part_s[1][t] + part_s[2][t] + part_s[3][t];
    }
}

// ---------------- launch ----------------

extern "C" void kernel_launch(void* const* d_in, const int* in_sizes, int n_in,
                              void* d_out, int out_size, void* d_ws, size_t ws_size,
                              hipStream_t stream) {
    const float* x    = (const float*)d_in[0];
    const float* werr = (const float*)d_in[1];
    const float* weu  = (const float*)d_in[2];
    const float* wlv  = (const float*)d_in[3];
    const float* wlu  = (const float*)d_in[4];
    const int*   roots = (const int*)d_in[5];
    const int*   nbrs  = (const int*)d_in[6];
    const int*   eidx  = (const int*)d_in[7];

    const int N = in_sizes[0] / F;
    const int B = in_sizes[5];
    const int E = in_sizes[7] / 2;
    const int* erow = eidx;
    const int* ecol = eidx + E;

    float* out  = (float*)d_out;
    float* buf0 = (float*)d_ws;       // int count -> float deg_inv (in place)
    float* buf1 = buf0 + N;           // nbr_sum -> n_imp (in place)

    const int TB = 256;
    // zero both tables (int 0 == float 0.0 bit pattern)
    zero_kernel<<<(2 * N + TB - 1) / TB, TB, 0, stream>>>(buf0, 2 * N);
    deg_kernel<<<(E + TB - 1) / TB, TB, 0, stream>>>(erow, E, (int*)buf0);
    deginv_kernel<<<(N + TB - 1) / TB, TB, 0, stream>>>((int*)buf0, N);
    nbrsum_kernel<<<(E + TB - 1) / TB, TB, 0, stream>>>(erow, ecol, E, buf0, buf1);
    nimp_kernel<<<(N + TB - 1) / TB, TB, 0, stream>>>(buf0, buf1, N);

    sampler_main<<<B, 512, 0, stream>>>(x, werr, weu, wlv, wlu,
                                        roots, nbrs, buf1, out);
}

// Round 2
// 366.433 us; speedup vs baseline: 1.2564x; 1.2564x over previous
//
#include <hip/hip_runtime.h>
#include <hip/hip_bf16.h>

// Problem constants (fixed shapes from setup_inputs):
// N=500000, F=128, B=1024, K=256, E=4000000
constexpr int F = 128;
constexpr int K = 256;

// ---------------- importance chain ----------------

__global__ void zero_kernel(int* p, int n) {
    int i = blockIdx.x * blockDim.x + threadIdx.x;
    if (i < n) p[i] = 0;
}

// mark nodes that appear in `neighbors` (the only places n_imp is read)
__global__ void bitmap_kernel(const int* __restrict__ nbrs, int M, unsigned* __restrict__ bm) {
    int i = blockIdx.x * blockDim.x + threadIdx.x;
    if (i < M) {
        int v = nbrs[i];
        unsigned m = 1u << (v & 31);
        unsigned* w = bm + (v >> 5);
        if (!(*w & m)) atomicOr(w, m);
    }
}

__global__ void deg_kernel(const int* __restrict__ row, int E, int* cnt) {
    int e = blockIdx.x * blockDim.x + threadIdx.x;
    if (e < E) atomicAdd(&cnt[row[e]], 1);
}

// in-place: read int count, write float deg_inv (same buffer)
__global__ void deginv_kernel(int* buf, int N) {
    int i = blockIdx.x * blockDim.x + threadIdx.x;
    if (i < N) {
        int c = buf[i];
        float dinv = 1.0f / (float)(c + 1);   // +1 self loop
        ((float*)buf)[i] = dinv;
    }
}

__global__ void nbrsum_kernel(const int* __restrict__ row, const int* __restrict__ col,
                              int E, const float* __restrict__ deg_inv,
                              const unsigned* __restrict__ bm, float* nbr_sum) {
    int e = blockIdx.x * blockDim.x + threadIdx.x;
    if (e < E) {
        int r = row[e];
        if ((bm[r >> 5] >> (r & 31)) & 1u) {
            unsafeAtomicAdd(&nbr_sum[r], deg_inv[col[e]]);
        }
    }
}

// in-place: nbr_sum buffer becomes n_imp
__global__ void nimp_kernel(const float* __restrict__ deg_inv, float* buf, int N) {
    int i = blockIdx.x * blockDim.x + threadIdx.x;
    if (i < N) {
        float dinv = deg_inv[i];
        float s = dinv * (buf[i] + dinv);
        buf[i] = sqrtf(fmaxf(s, 0.0f));
    }
}

// ---------------- fused scoring + aggregation ----------------
// One block per root b. Stage x_u[b] (256x128 f32 = 128KB) in LDS once.

__global__ __launch_bounds__(512) void sampler_main(
    const float* __restrict__ x,
    const float* __restrict__ w_ego_root,
    const float* __restrict__ w_ego_u,
    const float* __restrict__ w_layer_v,
    const float* __restrict__ w_layer_u,
    const int* __restrict__ roots,
    const int* __restrict__ neighbors,
    const float* __restrict__ n_imp,
    float* __restrict__ out)
{
    __shared__ __align__(16) float tile[K][F];   // 128 KB
    __shared__ float g_s[F];      // x_root*w_ego_root*w_ego_u  (ego dot weights)
    __shared__ float weu_s[F];    // w_ego_u
    __shared__ float wlu_s[F];    // w_layer_u
    __shared__ float ego_s[K];
    __shared__ float pre_s[K];
    __shared__ float praw_s[K];
    __shared__ float wgt_s[K];
    __shared__ float part_s[4][F];
    __shared__ float scal_s[4];   // [0]=na (clamped), [1]=h_v, [2]=layer norm
    __shared__ int   nbr_s[K];

    const int b = blockIdx.x;
    const int t = threadIdx.x;
    const int root = roots[b];
    const int* nbr = neighbors + (size_t)b * K;

    if (t < K) nbr_s[t] = nbr[t];
    if (t < F) {
        float xr  = x[(size_t)root * F + t];
        float hr  = xr * w_ego_root[t];
        float weu = w_ego_u[t];
        g_s[t]   = hr * weu;
        weu_s[t] = weu;
        wlu_s[t] = w_layer_u[t];
        pre_s[t] = hr * hr;                 // temp: na^2 partials
        ego_s[t] = xr * w_layer_v[t];       // temp: h_v partials
    }
    __syncthreads();

    // wave 0: reduce na^2 and h_v over 128 temps
    if (t < 64) {
        float a = pre_s[t] + pre_s[t + 64];
        float h = ego_s[t] + ego_s[t + 64];
        for (int m = 1; m < 64; m <<= 1) {
            a += __shfl_xor(a, m);
            h += __shfl_xor(h, m);
        }
        if (t == 0) {
            scal_s[0] = fmaxf(sqrtf(a), 1e-6f);
            scal_s[1] = h;
        }
    }

    // all threads: stage x_u tile into LDS (16B per lane, coalesced per row)
    for (int idx = t; idx < K * (F / 4); idx += 512) {
        int k  = idx >> 5;          // F/4 == 32 float4 per row
        int f4 = idx & 31;
        float4 v = ((const float4*)(x + (size_t)nbr_s[k] * F))[f4];
        ((float4*)tile[k])[f4] = v;
    }
    __syncthreads();

    // scoring: wave w handles k = w, w+8, ...; lane owns 2 features
    {
        const int wave = t >> 6;
        const int lane = t & 63;
        const float na = scal_s[0];
        const float hv = scal_s[1];
        const int f0 = lane * 2;
        const float g0 = g_s[f0],  g1 = g_s[f0 + 1];
        const float e0w = weu_s[f0], e1w = weu_s[f0 + 1];
        const float l0 = wlu_s[f0], l1 = wlu_s[f0 + 1];
        for (int k = wave; k < K; k += 8) {
            float2 v = ((const float2*)tile[k])[lane];
            float d   = g0 * v.x + g1 * v.y;
            float u0  = v.x * e0w, u1 = v.y * e1w;
            float nb2 = u0 * u0 + u1 * u1;
            float hu  = l0 * v.x + l1 * v.y;
            for (int m = 1; m < 64; m <<= 1) {
                d   += __shfl_xor(d, m);
                nb2 += __shfl_xor(nb2, m);
                hu  += __shfl_xor(hu, m);
            }
            if (lane == 0) {
                float nb = fmaxf(sqrtf(nb2), 1e-6f);
                ego_s[k] = d / (na * nb);
                pre_s[k] = fmaxf(hv + hu, 0.0f);
            }
        }
    }
    __syncthreads();

    // layer norm over k
    if (t < 64) {
        float s = 0.0f;
        for (int k = t; k < K; k += 64) s += pre_s[k] * pre_s[k];
        for (int m = 1; m < 64; m <<= 1) s += __shfl_xor(s, m);
        if (t == 0) scal_s[2] = fmaxf(sqrtf(s), 1e-12f);
    }
    __syncthreads();

    if (t < K) {
        float layer = pre_s[t] / scal_s[2];
        praw_s[t] = (0.5f * ego_s[t] + 0.5f * layer) * n_imp[nbr_s[t]];
    }
    __syncthreads();

    if (t < K) {
        float pn = praw_s[0] + 1e-7f;
        float pu = praw_s[t] / pn + 1.0f;
        float pc = fminf(fmaxf(pu, 0.01f), 1.0f);
        wgt_s[t] = (pu > 0.0f) ? pc : 0.0f;
    }
    __syncthreads();

    // weighted aggregation out[b,f] = sum_k w[k] * tile[k][f]
    {
        int f   = t & (F - 1);
        int grp = t >> 7;           // 4 groups of 64 k each
        float acc = 0.0f;
        int k0 = grp * 64;
        for (int k = k0; k < k0 + 64; ++k)
            acc += wgt_s[k] * tile[k][f];
        part_s[grp][f] = acc;
    }
    __syncthreads();

    if (t < F) {
        out[(size_t)b * F + t] =
            part_s[0][t] + part_s[1][t] + part_s[2][t] + part_s[3][t];
    }
}

// ---------------- launch ----------------

extern "C" void kernel_launch(void* const* d_in, const int* in_sizes, int n_in,
                              void* d_out, int out_size, void* d_ws, size_t ws_size,
                              hipStream_t stream) {
    const float* x    = (const float*)d_in[0];
    const float* werr = (const float*)d_in[1];
    const float* weu  = (const float*)d_in[2];
    const float* wlv  = (const float*)d_in[3];
    const float* wlu  = (const float*)d_in[4];
    const int*   roots = (const int*)d_in[5];
    const int*   nbrs  = (const int*)d_in[6];
    const int*   eidx  = (const int*)d_in[7];

    const int N = in_sizes[0] / F;
    const int B = in_sizes[5];
    const int M = in_sizes[6];       // B*K
    const int E = in_sizes[7] / 2;
    const int* erow = eidx;
    const int* ecol = eidx + E;

    float* out  = (float*)d_out;
    float* buf0 = (float*)d_ws;            // int count -> float deg_inv (in place)
    float* buf1 = buf0 + N;                // nbr_sum -> n_imp (in place)
    unsigned* bm = (unsigned*)(buf1 + N);  // needed-node bitmap
    const int NW = (N + 31) / 32;

    const int TB = 256;
    // zero tables + bitmap (int 0 == float 0.0 bit pattern)
    zero_kernel<<<(2 * N + NW + TB - 1) / TB, TB, 0, stream>>>((int*)buf0, 2 * N + NW);
    bitmap_kernel<<<(M + TB - 1) / TB, TB, 0, stream>>>(nbrs, M, bm);
    deg_kernel<<<(E + TB - 1) / TB, TB, 0, stream>>>(erow, E, (int*)buf0);
    deginv_kernel<<<(N + TB - 1) / TB, TB, 0, stream>>>((int*)buf0, N);
    nbrsum_kernel<<<(E + TB - 1) / TB, TB, 0, stream>>>(erow, ecol, E, buf0, bm, buf1);
    nimp_kernel<<<(N + TB - 1) / TB, TB, 0, stream>>>(buf0, buf1, N);

    sampler_main<<<B, 512, 0, stream>>>(x, werr, weu, wlv, wlu,
                                        roots, nbrs, buf1, out);
}

// Round 3
// 345.259 us; speedup vs baseline: 1.3334x; 1.0613x over previous
//
#include <hip/hip_runtime.h>
#include <hip/hip_bf16.h>

// Problem constants (fixed shapes from setup_inputs):
// N=500000, F=128, B=1024, K=256, E=4000000
constexpr int F = 128;
constexpr int K = 256;
constexpr int NXCD = 8;
constexpr float FXSCALE = 8388608.0f;      // 2^23 fixed-point scale
constexpr float FXINV   = 1.0f / 8388608.0f;

__device__ __forceinline__ unsigned xcc_id() {
    unsigned x;
    asm volatile("s_getreg_b32 %0, hwreg(HW_REG_XCC_ID)" : "=s"(x));
    return x & (NXCD - 1);
}

// ---------------- importance chain (XCD-private L2-resident atomics) --------

// mark nodes that appear in `neighbors` (the only places n_imp is read)
__global__ void bitmap_kernel(const int* __restrict__ nbrs, int M, unsigned* __restrict__ bm) {
    int i = blockIdx.x * blockDim.x + threadIdx.x;
    if (i < M) {
        int v = nbrs[i];
        unsigned m = 1u << (v & 31);
        unsigned* w = bm + (v >> 5);
        if (!(*w & m)) atomicOr(w, m);
    }
}

__global__ void deg8_kernel(const int* __restrict__ row, int E, int* __restrict__ tabs, int N) {
    int e = blockIdx.x * blockDim.x + threadIdx.x;
    if (e < E) {
        int* tab = tabs + (size_t)xcc_id() * N;
        __hip_atomic_fetch_add(&tab[row[e]], 1, __ATOMIC_RELAXED, __HIP_MEMORY_SCOPE_WORKGROUP);
    }
}

// fold 8 count tables -> quantized deg_inv (int, 2^23 scale); re-zero tables
__global__ void degq_reduce_kernel(int* __restrict__ tabs, int N, int* __restrict__ degq) {
    int i = blockIdx.x * blockDim.x + threadIdx.x;
    if (i < N) {
        int c = 0;
        #pragma unroll
        for (int x = 0; x < NXCD; ++x) {
            c += tabs[(size_t)x * N + i];
            tabs[(size_t)x * N + i] = 0;
        }
        float dinv = 1.0f / (float)(c + 1);   // +1 self loop
        degq[i] = (int)(dinv * FXSCALE + 0.5f);
    }
}

__global__ void nbrsum8_kernel(const int* __restrict__ row, const int* __restrict__ col,
                               int E, const int* __restrict__ degq,
                               const unsigned* __restrict__ bm, int* __restrict__ tabs, int N) {
    int e = blockIdx.x * blockDim.x + threadIdx.x;
    if (e < E) {
        int r = row[e];
        if ((bm[r >> 5] >> (r & 31)) & 1u) {
            int* tab = tabs + (size_t)xcc_id() * N;
            __hip_atomic_fetch_add(&tab[r], degq[col[e]], __ATOMIC_RELAXED, __HIP_MEMORY_SCOPE_WORKGROUP);
        }
    }
}

__global__ void nimp8_kernel(const int* __restrict__ tabs, const int* __restrict__ degq,
                             int N, float* __restrict__ nimp) {
    int i = blockIdx.x * blockDim.x + threadIdx.x;
    if (i < N) {
        long long s = 0;
        #pragma unroll
        for (int x = 0; x < NXCD; ++x) s += tabs[(size_t)x * N + i];
        float dinv = (float)degq[i] * FXINV;
        float nbr  = (float)s * FXINV;
        float v = dinv * (nbr + dinv);
        nimp[i] = sqrtf(fmaxf(v, 0.0f));
    }
}

// ---------------- fallback (agent-scope) path for small ws ----------------

__global__ void zero_kernel(int* p, int n) {
    int i = blockIdx.x * blockDim.x + threadIdx.x;
    if (i < n) p[i] = 0;
}

__global__ void deg_kernel(const int* __restrict__ row, int E, int* cnt) {
    int e = blockIdx.x * blockDim.x + threadIdx.x;
    if (e < E) atomicAdd(&cnt[row[e]], 1);
}

__global__ void deginv_kernel(int* buf, int N) {
    int i = blockIdx.x * blockDim.x + threadIdx.x;
    if (i < N) {
        int c = buf[i];
        ((float*)buf)[i] = 1.0f / (float)(c + 1);
    }
}

__global__ void nbrsum_kernel(const int* __restrict__ row, const int* __restrict__ col,
                              int E, const float* __restrict__ deg_inv,
                              const unsigned* __restrict__ bm, float* nbr_sum) {
    int e = blockIdx.x * blockDim.x + threadIdx.x;
    if (e < E) {
        int r = row[e];
        if ((bm[r >> 5] >> (r & 31)) & 1u)
            unsafeAtomicAdd(&nbr_sum[r], deg_inv[col[e]]);
    }
}

__global__ void nimp_kernel(const float* __restrict__ deg_inv, float* buf, int N) {
    int i = blockIdx.x * blockDim.x + threadIdx.x;
    if (i < N) {
        float dinv = deg_inv[i];
        float s = dinv * (buf[i] + dinv);
        buf[i] = sqrtf(fmaxf(s, 0.0f));
    }
}

// ---------------- fused scoring + aggregation ----------------
// One block per root b (1024 threads). Stage x_u[b] (256x128 f32 = 128KB) in LDS.

__global__ __launch_bounds__(1024) void sampler_main(
    const float* __restrict__ x,
    const float* __restrict__ w_ego_root,
    const float* __restrict__ w_ego_u,
    const float* __restrict__ w_layer_v,
    const float* __restrict__ w_layer_u,
    const int* __restrict__ roots,
    const int* __restrict__ neighbors,
    const float* __restrict__ n_imp,
    float* __restrict__ out)
{
    __shared__ __align__(16) float tile[K][F];   // 128 KB
    __shared__ float g_s[F];
    __shared__ float weu_s[F];
    __shared__ float wlu_s[F];
    __shared__ float ego_s[K];
    __shared__ float pre_s[K];
    __shared__ float praw_s[K];
    __shared__ float wgt_s[K];
    __shared__ float part_s[8][F];
    __shared__ float scal_s[4];   // [0]=na (clamped), [1]=h_v, [2]=layer norm
    __shared__ int   nbr_s[K];

    const int b = blockIdx.x;
    const int t = threadIdx.x;
    const int root = roots[b];
    const int* nbr = neighbors + (size_t)b * K;

    if (t < K) nbr_s[t] = nbr[t];
    if (t < F) {
        float xr  = x[(size_t)root * F + t];
        float hr  = xr * w_ego_root[t];
        float weu = w_ego_u[t];
        g_s[t]   = hr * weu;
        weu_s[t] = weu;
        wlu_s[t] = w_layer_u[t];
        pre_s[t] = hr * hr;                 // temp: na^2 partials
        ego_s[t] = xr * w_layer_v[t];       // temp: h_v partials
    }
    __syncthreads();

    // wave 0: reduce na^2 and h_v over 128 temps
    if (t < 64) {
        float a = pre_s[t] + pre_s[t + 64];
        float h = ego_s[t] + ego_s[t + 64];
        for (int m = 1; m < 64; m <<= 1) {
            a += __shfl_xor(a, m);
            h += __shfl_xor(h, m);
        }
        if (t == 0) {
            scal_s[0] = fmaxf(sqrtf(a), 1e-6f);
            scal_s[1] = h;
        }
    }

    // all threads: stage x_u tile into LDS (16B per lane, coalesced per row)
    for (int idx = t; idx < K * (F / 4); idx += 1024) {
        int k  = idx >> 5;          // F/4 == 32 float4 per row
        int f4 = idx & 31;
        float4 v = ((const float4*)(x + (size_t)nbr_s[k] * F))[f4];
        ((float4*)tile[k])[f4] = v;
    }
    __syncthreads();

    // scoring: wave w handles k = w, w+16, ...; lane owns 2 features
    {
        const int wave = t >> 6;
        const int lane = t & 63;
        const float na = scal_s[0];
        const float hv = scal_s[1];
        const int f0 = lane * 2;
        const float g0 = g_s[f0],  g1 = g_s[f0 + 1];
        const float e0w = weu_s[f0], e1w = weu_s[f0 + 1];
        const float l0 = wlu_s[f0], l1 = wlu_s[f0 + 1];
        for (int k = wave; k < K; k += 16) {
            float2 v = ((const float2*)tile[k])[lane];
            float d   = g0 * v.x + g1 * v.y;
            float u0  = v.x * e0w, u1 = v.y * e1w;
            float nb2 = u0 * u0 + u1 * u1;
            float hu  = l0 * v.x + l1 * v.y;
            for (int m = 1; m < 64; m <<= 1) {
                d   += __shfl_xor(d, m);
                nb2 += __shfl_xor(nb2, m);
                hu  += __shfl_xor(hu, m);
            }
            if (lane == 0) {
                float nb = fmaxf(sqrtf(nb2), 1e-6f);
                ego_s[k] = d / (na * nb);
                pre_s[k] = fmaxf(hv + hu, 0.0f);
            }
        }
    }
    __syncthreads();

    // layer norm over k
    if (t < 64) {
        float s = 0.0f;
        for (int k = t; k < K; k += 64) s += pre_s[k] * pre_s[k];
        for (int m = 1; m < 64; m <<= 1) s += __shfl_xor(s, m);
        if (t == 0) scal_s[2] = fmaxf(sqrtf(s), 1e-12f);
    }
    __syncthreads();

    if (t < K) {
        float layer = pre_s[t] / scal_s[2];
        praw_s[t] = (0.5f * ego_s[t] + 0.5f * layer) * n_imp[nbr_s[t]];
    }
    __syncthreads();

    if (t < K) {
        float pn = praw_s[0] + 1e-7f;
        float pu = praw_s[t] / pn + 1.0f;
        float pc = fminf(fmaxf(pu, 0.01f), 1.0f);
        wgt_s[t] = (pu > 0.0f) ? pc : 0.0f;
    }
    __syncthreads();

    // weighted aggregation out[b,f] = sum_k w[k] * tile[k][f]
    {
        int f   = t & (F - 1);
        int grp = t >> 7;           // 8 groups of 32 k each
        float acc = 0.0f;
        int k0 = grp * 32;
        for (int k = k0; k < k0 + 32; ++k)
            acc += wgt_s[k] * tile[k][f];
        part_s[grp][f] = acc;
    }
    __syncthreads();

    if (t < F) {
        float r = 0.0f;
        #pragma unroll
        for (int g = 0; g < 8; ++g) r += part_s[g][t];
        out[(size_t)b * F + t] = r;
    }
}

// ---------------- launch ----------------

extern "C" void kernel_launch(void* const* d_in, const int* in_sizes, int n_in,
                              void* d_out, int out_size, void* d_ws, size_t ws_size,
                              hipStream_t stream) {
    const float* x    = (const float*)d_in[0];
    const float* werr = (const float*)d_in[1];
    const float* weu  = (const float*)d_in[2];
    const float* wlv  = (const float*)d_in[3];
    const float* wlu  = (const float*)d_in[4];
    const int*   roots = (const int*)d_in[5];
    const int*   nbrs  = (const int*)d_in[6];
    const int*   eidx  = (const int*)d_in[7];

    const int N = in_sizes[0] / F;
    const int B = in_sizes[5];
    const int M = in_sizes[6];       // B*K
    const int E = in_sizes[7] / 2;
    const int* erow = eidx;
    const int* ecol = eidx + E;

    float* out = (float*)d_out;
    const int NW = (N + 31) / 32;
    const int TB = 256;

    size_t need = ((size_t)NXCD * N + NW + N + N) * 4;

    if (ws_size >= need) {
        // fast path: XCD-private L2-resident atomics
        int*      tabs = (int*)d_ws;                      // 8 x N
        unsigned* bm   = (unsigned*)(tabs + (size_t)NXCD * N);
        int*      degq = (int*)(bm + NW);
        float*    nimp = (float*)(degq + N);

        hipMemsetAsync(d_ws, 0, ((size_t)NXCD * N + NW) * 4, stream);
        bitmap_kernel<<<(M + TB - 1) / TB, TB, 0, stream>>>(nbrs, M, bm);
        deg8_kernel<<<(E + TB - 1) / TB, TB, 0, stream>>>(erow, E, tabs, N);
        degq_reduce_kernel<<<(N + TB - 1) / TB, TB, 0, stream>>>(tabs, N, degq);
        nbrsum8_kernel<<<(E + TB - 1) / TB, TB, 0, stream>>>(erow, ecol, E, degq, bm, tabs, N);
        nimp8_kernel<<<(N + TB - 1) / TB, TB, 0, stream>>>(tabs, degq, N, nimp);
        sampler_main<<<B, 1024, 0, stream>>>(x, werr, weu, wlv, wlu, roots, nbrs, nimp, out);
    } else {
        // fallback: agent-scope atomics
        float* buf0 = (float*)d_ws;
        float* buf1 = buf0 + N;
        unsigned* bm = (unsigned*)(buf1 + N);

        zero_kernel<<<(2 * N + NW + TB - 1) / TB, TB, 0, stream>>>((int*)buf0, 2 * N + NW);
        bitmap_kernel<<<(M + TB - 1) / TB, TB, 0, stream>>>(nbrs, M, bm);
        deg_kernel<<<(E + TB - 1) / TB, TB, 0, stream>>>(erow, E, (int*)buf0);
        deginv_kernel<<<(N + TB - 1) / TB, TB, 0, stream>>>((int*)buf0, N);
        nbrsum_kernel<<<(E + TB - 1) / TB, TB, 0, stream>>>(erow, ecol, E, buf0, bm, buf1);
        nimp_kernel<<<(N + TB - 1) / TB, TB, 0, stream>>>(buf0, buf1, N);
        sampler_main<<<B, 1024, 0, stream>>>(x, werr, weu, wlv, wlu, roots, nbrs, buf1, out);
    }
}